// Round 7
// baseline (92.764 us; speedup 1.0000x reference)
//
#include <hip/hip_runtime.h>
#include <hip/hip_bf16.h>
#include <math.h>

#define BB 4
#define CC 64
#define OO 64
#define HH 128
#define WW 128
#define HWsz (HH * WW)

typedef __attribute__((ext_vector_type(8))) short short8;
typedef __attribute__((ext_vector_type(4))) float floatx4;

static __device__ __forceinline__ short f2bf(float f) {
    __hip_bfloat16 h = __float2bfloat16(f);   // RNE
    union { __hip_bfloat16 h; short s; } u; u.h = h; return u.s;
}
static __device__ __forceinline__ float bf2f(short s) {
    union { unsigned u; float f; } v;
    v.u = ((unsigned)(unsigned short)s) << 16;
    return v.f;
}

// ---------------------------------------------------------------------------
// pre: (blocks 0..511)  x NCHW f32 -> xh NHWC bf16
//      (blocks 512..727) fragment-ordered weight repack:
//  waf[((k*2+kh)*4+m)*512 + lane*8 + j] =
//      bf16(wgt[(m*16+(lane&15))*576 + (kh*32+(lane>>4)*8+j)*9 + k])
//  wcf[((k*2+kh)*2+m)*512 + lane*8 + j] = offset(18)/mask(9) rows, 0-padded
// ---------------------------------------------------------------------------
__global__ __launch_bounds__(256) void pre_kernel(
    const float* __restrict__ x, const float* __restrict__ wgt,
    const float* __restrict__ ow, const float* __restrict__ mw,
    short* __restrict__ xh, short* __restrict__ waf, short* __restrict__ wcf)
{
    int bid = blockIdx.x;
    int tid = threadIdx.x;
    if (bid < 512) {
        int b = bid >> 7, y = bid & 127;
        int px = tid & 127;
        int ch = (tid >> 7) * 32;
        const float* xp = x + (size_t)(b * CC + ch) * HWsz + y * WW + px;
        short buf[32];
#pragma unroll
        for (int q = 0; q < 32; ++q)
            buf[q] = f2bf(xp[(size_t)q * HWsz]);
        short* dst = xh + ((size_t)(b * HH + y) * WW + px) * 64 + ch;
#pragma unroll
        for (int q = 0; q < 4; ++q)
            *(short8*)&dst[q * 8] = *(const short8*)&buf[q * 8];
    } else {
        int i = (bid - 512) * 256 + tid;
        if (i < 36864) {
            int j = i & 7, lane = (i >> 3) & 63, rest = i >> 9;
            int m = rest & 3, kh = (rest >> 2) & 1, k = rest >> 3;
            int o = m * 16 + (lane & 15);
            int c = kh * 32 + ((lane >> 4) << 3) + j;
            waf[i] = f2bf(wgt[o * 576 + c * 9 + k]);
        } else if (i < 55296) {
            int t = i - 36864;
            int j = t & 7, lane = (t >> 3) & 63, rest = t >> 9;
            int m = rest & 1, kh = (rest >> 1) & 1, k = rest >> 2;
            int o = m * 16 + (lane & 15);
            int c = kh * 32 + ((lane >> 4) << 3) + j;
            float v = 0.f;
            if (o < 18) v = ow[o * 576 + c * 9 + k];
            else if (o < 27) v = mw[(o - 18) * 576 + c * 9 + k];
            wcf[t] = f2bf(v);
        }
    }
}

// ---------------------------------------------------------------------------
// fused kernel, K-split edition. Per block: 32 px (2 strips x 16 px), 4 waves:
//   wave (s, khalf) = strip s, channel-half khalf.
//   phase 1: offset/mask conv, full K, wave owns om rows [khalf*16, +16)
//            -> om[strip][27][16] in LDS; one barrier.
//   phase 2: per tap: 4 corner gathers (own 32-ch half), in-register bilinear
//            blend (mask folded), 4 weight fragments from L1-hot global,
//            4 MFMA (K=32). Depth-1 pipeline across taps.
//   epilogue: khalf=1 partials -> LDS, barrier, khalf=0 adds + writes out.
// Grid 2048 = 8 blocks/CU = 32 waves/CU.
// ---------------------------------------------------------------------------
__global__ __launch_bounds__(256, 8) void fused_kernel(
    const short* __restrict__ xh, const short* __restrict__ waf,
    const short* __restrict__ wcf, const float* __restrict__ ob,
    const float* __restrict__ mb, float* __restrict__ out)
{
    __shared__ float om[2 * 27 * 16];      // 3456 B
    __shared__ float red[8 * 64 * 4];      // 8192 B  [m*2+s][lane][4]

    int tid = threadIdx.x;
    int gid = blockIdx.x;
    // XCD-bijective swizzle: 2048 blocks = 8 XCDs x 256 contiguous
    int sid = (gid & 7) * 256 + (gid >> 3);
    int b = sid >> 9;
    int r = sid & 511;
    int h = r >> 2;
    int p0 = (r & 3) << 5;

    int wv = tid >> 6;
    int lane = tid & 63;
    int s = wv & 1;            // strip within block
    int khalf = wv >> 1;       // channel half (phase 2) / row half (phase 1)
    int g = lane >> 4;
    int pl = lane & 15;
    int goff = g * 8;                 // phase-1 channel octet (lower half)
    int coff = khalf * 32 + goff;     // phase-2 channel octet
    int xw = p0 + s * 16 + pl;

    const short* xhb = xh + ((size_t)b << 20);
    float* omw = &om[s * 27 * 16];

    // ---------------- phase 1: offset/mask conv (full K, half rows) --------
    floatx4 accC = {0.f, 0.f, 0.f, 0.f};

#define CADDR(K, P, V) do {                                                  \
    int ky = (K) / 3, kx = (K) - ky * 3;                                     \
    int yy = h + ky - 1, xx = xw + kx - 1;                                   \
    V = (yy >= 0) & (yy < HH) & (xx >= 0) & (xx < WW);                       \
    int yc = min(max(yy, 0), HH - 1), xc = min(max(xx, 0), WW - 1);          \
    P = ((yc * WW + xc) << 6) + goff;                                        \
} while (0)

#define CONVTAP(K, S0, S1, V) do {                                           \
    const short* wp = wcf + ((((K) * 4) + khalf) << 9) + lane * 8;           \
    short8 w0 = *(const short8*)(wp);                                        \
    short8 w1 = *(const short8*)(wp + (2 << 9));                             \
    short8 z = {0, 0, 0, 0, 0, 0, 0, 0};                                     \
    short8 a0 = S0, a1 = S1;                                                 \
    if (!(V)) { a0 = z; a1 = z; }                                            \
    accC = __builtin_amdgcn_mfma_f32_16x16x32_bf16(w0, a0, accC, 0, 0, 0);   \
    accC = __builtin_amdgcn_mfma_f32_16x16x32_bf16(w1, a1, accC, 0, 0, 0);   \
} while (0)

    {
        bool vA, vB;
        int pa, pb;
        short8 A0, A1, B0, B1;
        CADDR(0, pa, vA);
        A0 = *(const short8*)(xhb + pa);
        A1 = *(const short8*)(xhb + pa + 32);
#pragma unroll 1
        for (int kp = 0; kp < 4; ++kp) {
            int k = kp * 2;
            CADDR(k + 1, pb, vB);
            B0 = *(const short8*)(xhb + pb);
            B1 = *(const short8*)(xhb + pb + 32);
            CONVTAP(k, A0, A1, vA);
            CADDR(k + 2, pa, vA);
            A0 = *(const short8*)(xhb + pa);
            A1 = *(const short8*)(xhb + pa + 32);
            CONVTAP(k + 1, B0, B1, vB);
        }
        CONVTAP(8, A0, A1, vA);
    }

    // om epilogue: wave owns rows khalf*16..khalf*16+15 of its strip
#pragma unroll
    for (int j = 0; j < 4; ++j) {
        int o = khalf * 16 + g * 4 + j;
        float v = accC[j];
        if (o < 18) omw[o * 16 + pl] = v + ob[o];
        else if (o < 27)
            omw[o * 16 + pl] = 1.0f / (1.0f + expf(-(v + mb[o - 18])));
    }
    __syncthreads();

    // ---------------- phase 2: deformable sampling + GEMM (K-split) -------
    floatx4 acc0 = {0.f, 0.f, 0.f, 0.f}, acc1 = {0.f, 0.f, 0.f, 0.f};
    floatx4 acc2 = {0.f, 0.f, 0.f, 0.f}, acc3 = {0.f, 0.f, 0.f, 0.f};

#define MKTAP(K, I00, I01, I10, I11, U00, U01, U10, U11) do {                \
    int ky = (K) / 3, kx = (K) - ky * 3;                                     \
    float oy = omw[(2 * (K)) * 16 + pl];                                     \
    float ox = omw[(2 * (K) + 1) * 16 + pl];                                 \
    float mk = omw[(18 + (K)) * 16 + pl];                                    \
    float py = oy + (float)(h + ky - 1);                                     \
    float qx = ox + (float)(xw + kx - 1);                                    \
    float y0f = floorf(py), x0f = floorf(qx);                                \
    float dyy = py - y0f, dxx = qx - x0f;                                    \
    int y0 = (int)y0f, x0 = (int)x0f;                                        \
    int y1 = y0 + 1, x1 = x0 + 1;                                            \
    bool vy0 = (y0 >= 0) & (y0 < HH), vy1 = (y1 >= 0) & (y1 < HH);           \
    bool vx0 = (x0 >= 0) & (x0 < WW), vx1 = (x1 >= 0) & (x1 < WW);           \
    U00 = (vy0 & vx0) ? (1.f - dyy) * (1.f - dxx) * mk : 0.f;                \
    U01 = (vy0 & vx1) ? (1.f - dyy) * dxx * mk : 0.f;                        \
    U10 = (vy1 & vx0) ? dyy * (1.f - dxx) * mk : 0.f;                        \
    U11 = (vy1 & vx1) ? dyy * dxx * mk : 0.f;                                \
    int yc0 = min(max(y0, 0), HH - 1), yc1 = min(max(y1, 0), HH - 1);        \
    int xc0 = min(max(x0, 0), WW - 1), xc1 = min(max(x1, 0), WW - 1);        \
    I00 = ((yc0 * WW + xc0) << 6) + coff;                                    \
    I01 = ((yc0 * WW + xc1) << 6) + coff;                                    \
    I10 = ((yc1 * WW + xc0) << 6) + coff;                                    \
    I11 = ((yc1 * WW + xc1) << 6) + coff;                                    \
} while (0)

#define ISSUE4(I00, I01, I10, I11, C00, C01, C10, C11) do {                  \
    C00 = *(const short8*)(xhb + I00); C01 = *(const short8*)(xhb + I01);    \
    C10 = *(const short8*)(xhb + I10); C11 = *(const short8*)(xhb + I11);    \
} while (0)

#define BLEND(T, R0, R1, R2, R3, U00, U01, U10, U11) do {                    \
    _Pragma("unroll") for (int jj = 0; jj < 8; ++jj) {                       \
        float sx = U00 * bf2f(R0[jj]) + U01 * bf2f(R1[jj])                   \
                 + U10 * bf2f(R2[jj]) + U11 * bf2f(R3[jj]);                  \
        T[jj] = f2bf(sx);                                                    \
    }                                                                        \
} while (0)

#define TAPMFMA(K, C00, C01, C10, C11, U00, U01, U10, U11) do {              \
    const short* wk = waf + ((((K) * 2) + khalf) << 11) + lane * 8;          \
    short8 q0 = *(const short8*)(wk + (0 << 9));                             \
    short8 q1 = *(const short8*)(wk + (1 << 9));                             \
    short8 q2 = *(const short8*)(wk + (2 << 9));                             \
    short8 q3 = *(const short8*)(wk + (3 << 9));                             \
    short8 bf;                                                               \
    BLEND(bf, C00, C01, C10, C11, U00, U01, U10, U11);                       \
    acc0 = __builtin_amdgcn_mfma_f32_16x16x32_bf16(q0, bf, acc0, 0, 0, 0);   \
    acc1 = __builtin_amdgcn_mfma_f32_16x16x32_bf16(q1, bf, acc1, 0, 0, 0);   \
    acc2 = __builtin_amdgcn_mfma_f32_16x16x32_bf16(q2, bf, acc2, 0, 0, 0);   \
    acc3 = __builtin_amdgcn_mfma_f32_16x16x32_bf16(q3, bf, acc3, 0, 0, 0);   \
} while (0)

    {
        int iA00, iA01, iA10, iA11, iB00, iB01, iB10, iB11;
        float uA00, uA01, uA10, uA11, uB00, uB01, uB10, uB11;
        short8 cA00, cA01, cA10, cA11;
        short8 cB00, cB01, cB10, cB11;

        MKTAP(0, iA00, iA01, iA10, iA11, uA00, uA01, uA10, uA11);
        ISSUE4(iA00, iA01, iA10, iA11, cA00, cA01, cA10, cA11);
#pragma unroll 1
        for (int kp = 0; kp < 4; ++kp) {
            int k = kp * 2;
            MKTAP(k + 1, iB00, iB01, iB10, iB11, uB00, uB01, uB10, uB11);
            ISSUE4(iB00, iB01, iB10, iB11, cB00, cB01, cB10, cB11);
            TAPMFMA(k, cA00, cA01, cA10, cA11, uA00, uA01, uA10, uA11);
            MKTAP(k + 2, iA00, iA01, iA10, iA11, uA00, uA01, uA10, uA11);
            ISSUE4(iA00, iA01, iA10, iA11, cA00, cA01, cA10, cA11);
            TAPMFMA(k + 1, cB00, cB01, cB10, cB11, uB00, uB01, uB10, uB11);
        }
        TAPMFMA(8, cA00, cA01, cA10, cA11, uA00, uA01, uA10, uA11);
    }

    // ---------------- cross-wave K-reduction + writeout --------------------
    if (khalf) {
        *(floatx4*)&red[((0 * 2 + s) * 64 + lane) * 4] = acc0;
        *(floatx4*)&red[((1 * 2 + s) * 64 + lane) * 4] = acc1;
        *(floatx4*)&red[((2 * 2 + s) * 64 + lane) * 4] = acc2;
        *(floatx4*)&red[((3 * 2 + s) * 64 + lane) * 4] = acc3;
    }
    __syncthreads();
    if (!khalf) {
        floatx4 r0 = *(const floatx4*)&red[((0 * 2 + s) * 64 + lane) * 4];
        floatx4 r1 = *(const floatx4*)&red[((1 * 2 + s) * 64 + lane) * 4];
        floatx4 r2 = *(const floatx4*)&red[((2 * 2 + s) * 64 + lane) * 4];
        floatx4 r3 = *(const floatx4*)&red[((3 * 2 + s) * 64 + lane) * 4];
        acc0 = acc0 + r0;
        acc1 = acc1 + r1;
        acc2 = acc2 + r2;
        acc3 = acc3 + r3;
        float* outp = out + (size_t)b * OO * HWsz + h * WW + p0 + s * 16 + pl;
#pragma unroll
        for (int j = 0; j < 4; ++j) outp[(size_t)(g * 4 + j) * HWsz] = acc0[j];
#pragma unroll
        for (int j = 0; j < 4; ++j) outp[(size_t)(16 + g * 4 + j) * HWsz] = acc1[j];
#pragma unroll
        for (int j = 0; j < 4; ++j) outp[(size_t)(32 + g * 4 + j) * HWsz] = acc2[j];
#pragma unroll
        for (int j = 0; j < 4; ++j) outp[(size_t)(48 + g * 4 + j) * HWsz] = acc3[j];
    }
}

extern "C" void kernel_launch(void* const* d_in, const int* in_sizes, int n_in,
                              void* d_out, int out_size, void* d_ws, size_t ws_size,
                              hipStream_t stream)
{
    const float* x   = (const float*)d_in[0];
    const float* ow  = (const float*)d_in[1];
    const float* ob  = (const float*)d_in[2];
    const float* mw  = (const float*)d_in[3];
    const float* mb  = (const float*)d_in[4];
    const float* wgt = (const float*)d_in[5];
    float* out = (float*)d_out;

    // ws: xh (4*16384*64 bf16 = 8.39MB) | waf (36864 bf16) | wcf (18432 bf16)
    short* xh  = (short*)d_ws;
    short* waf = xh + (size_t)BB * HWsz * 64;
    short* wcf = waf + 36864;

    pre_kernel<<<dim3(512 + 216), dim3(256), 0, stream>>>(
        x, wgt, ow, mw, xh, waf, wcf);
    fused_kernel<<<dim3(2048), dim3(256), 0, stream>>>(
        xh, waf, wcf, ob, mb, out);
}

// Round 8
// 69.125 us; speedup vs baseline: 1.3420x; 1.3420x over previous
//
#include <hip/hip_runtime.h>
#include <math.h>

#define BB 4
#define CC 64
#define OO 64
#define HH 128
#define WW 128
#define HWsz (HH * WW)

typedef __attribute__((ext_vector_type(8))) _Float16 half8;
typedef __attribute__((ext_vector_type(4))) float floatx4;

// ---------------------------------------------------------------------------
// pre: (blocks 0..511)  x NCHW f32 -> xh NHWC f16
//      (blocks 512..727) fragment-ordered f16 weight repack:
//  waf[((k*2+kh)*4+m)*512 + lane*8 + j] =
//      f16(wgt[(m*16+(lane&15))*576 + (kh*32+(lane>>4)*8+j)*9 + k])
//  wcf[((k*2+kh)*2+m)*512 + lane*8 + j] = offset(18)/mask(9) rows, 0-padded
// ---------------------------------------------------------------------------
__global__ __launch_bounds__(256) void pre_kernel(
    const float* __restrict__ x, const float* __restrict__ wgt,
    const float* __restrict__ ow, const float* __restrict__ mw,
    _Float16* __restrict__ xh, _Float16* __restrict__ waf,
    _Float16* __restrict__ wcf)
{
    int bid = blockIdx.x;
    int tid = threadIdx.x;
    if (bid < 512) {
        int b = bid >> 7, y = bid & 127;
        int px = tid & 127;
        int ch = (tid >> 7) * 32;
        const float* xp = x + (size_t)(b * CC + ch) * HWsz + y * WW + px;
        _Float16 buf[32];
#pragma unroll
        for (int q = 0; q < 32; ++q)
            buf[q] = (_Float16)xp[(size_t)q * HWsz];
        _Float16* dst = xh + ((size_t)(b * HH + y) * WW + px) * 64 + ch;
#pragma unroll
        for (int q = 0; q < 4; ++q)
            *(half8*)&dst[q * 8] = *(const half8*)&buf[q * 8];
    } else {
        int i = (bid - 512) * 256 + tid;
        if (i < 36864) {
            int j = i & 7, lane = (i >> 3) & 63, rest = i >> 9;
            int m = rest & 3, kh = (rest >> 2) & 1, k = rest >> 3;
            int o = m * 16 + (lane & 15);
            int c = kh * 32 + ((lane >> 4) << 3) + j;
            waf[i] = (_Float16)wgt[o * 576 + c * 9 + k];
        } else if (i < 55296) {
            int t = i - 36864;
            int j = t & 7, lane = (t >> 3) & 63, rest = t >> 9;
            int m = rest & 1, kh = (rest >> 1) & 1, k = rest >> 2;
            int o = m * 16 + (lane & 15);
            int c = kh * 32 + ((lane >> 4) << 3) + j;
            float v = 0.f;
            if (o < 18) v = ow[o * 576 + c * 9 + k];
            else if (o < 27) v = mw[(o - 18) * 576 + c * 9 + k];
            wcf[t] = (_Float16)v;
        }
    }
}

// ---------------------------------------------------------------------------
// fused kernel (fp16). 1024 blocks x 256 thr, wave = 16-px strip, full 64 ch.
//   phase 1: offset/mask conv, pair-pipelined, wave-local om (no barrier)
//   phase 2: 9 taps fully unrolled, 2-set rotation, corners issued 2 taps
//            ahead; packed-f16 bilinear blend; f16 MFMA; global f16 weights.
// ---------------------------------------------------------------------------
__global__ __launch_bounds__(256, 3) void fused_kernel(
    const _Float16* __restrict__ xh, const _Float16* __restrict__ waf,
    const _Float16* __restrict__ wcf, const float* __restrict__ ob,
    const float* __restrict__ mb, float* __restrict__ out)
{
    __shared__ float om[4 * 27 * 16];   // per-wave 27x16, f32

    int tid = threadIdx.x;
    int gid = blockIdx.x;
    // XCD-bijective swizzle: 1024 blocks = 8 XCDs x 128 contiguous
    int sid = (gid & 7) * 128 + (gid >> 3);
    int b = sid >> 8;
    int r = sid & 255;
    int h = r >> 1;
    int p0 = (r & 1) << 6;

    int wv = tid >> 6;
    int lane = tid & 63;
    int g = lane >> 4;
    int pl = lane & 15;
    int goff = g * 8;
    int xw = p0 + wv * 16 + pl;

    const _Float16* xhb = xh + ((size_t)b << 20);
    float* omw = &om[wv * 27 * 16];

    // ---------------- phase 1: offset/mask conv (pipelined, f16) -----------
    floatx4 accC0 = {0.f, 0.f, 0.f, 0.f};
    floatx4 accC1 = {0.f, 0.f, 0.f, 0.f};

#define CADDR(K, P, V) do {                                                  \
    int ky = (K) / 3, kx = (K) - ky * 3;                                     \
    int yy = h + ky - 1, xx = xw + kx - 1;                                   \
    V = (yy >= 0) & (yy < HH) & (xx >= 0) & (xx < WW);                       \
    int yc = min(max(yy, 0), HH - 1), xc = min(max(xx, 0), WW - 1);          \
    P = ((yc * WW + xc) << 6) + goff;                                        \
} while (0)

#define CONVTAP(K, S0, S1, V) do {                                           \
    const _Float16* wp = wcf + ((K) << 11) + lane * 8;                       \
    half8 w00 = *(const half8*)(wp + (0 << 9));                              \
    half8 w01 = *(const half8*)(wp + (1 << 9));                              \
    half8 w10 = *(const half8*)(wp + (2 << 9));                              \
    half8 w11 = *(const half8*)(wp + (3 << 9));                              \
    half8 z = {0, 0, 0, 0, 0, 0, 0, 0};                                     \
    half8 a0 = (V) ? S0 : z;                                                 \
    half8 a1 = (V) ? S1 : z;                                                 \
    accC0 = __builtin_amdgcn_mfma_f32_16x16x32_f16(w00, a0, accC0, 0, 0, 0); \
    accC1 = __builtin_amdgcn_mfma_f32_16x16x32_f16(w01, a0, accC1, 0, 0, 0); \
    accC0 = __builtin_amdgcn_mfma_f32_16x16x32_f16(w10, a1, accC0, 0, 0, 0); \
    accC1 = __builtin_amdgcn_mfma_f32_16x16x32_f16(w11, a1, accC1, 0, 0, 0); \
} while (0)

    {
        bool vA, vB;
        int pa, pb;
        half8 A0, A1, B0, B1;
        CADDR(0, pa, vA);
        A0 = *(const half8*)(xhb + pa);
        A1 = *(const half8*)(xhb + pa + 32);
#pragma unroll 1
        for (int kp = 0; kp < 4; ++kp) {
            int k = kp * 2;
            CADDR(k + 1, pb, vB);
            B0 = *(const half8*)(xhb + pb);
            B1 = *(const half8*)(xhb + pb + 32);
            CONVTAP(k, A0, A1, vA);
            CADDR(k + 2, pa, vA);
            A0 = *(const half8*)(xhb + pa);
            A1 = *(const half8*)(xhb + pa + 32);
            CONVTAP(k + 1, B0, B1, vB);
        }
        CONVTAP(8, A0, A1, vA);
    }

    // om epilogue: wave-local (each wave owns all 27 rows of its strip)
#pragma unroll
    for (int j = 0; j < 4; ++j) {
        int o = g * 4 + j;
        omw[o * 16 + pl] = accC0[j] + ob[o];
        int o2 = 16 + g * 4 + j;
        float v = accC1[j];
        if (o2 < 18) omw[o2 * 16 + pl] = v + ob[o2];
        else if (o2 < 27)
            omw[o2 * 16 + pl] = 1.0f / (1.0f + expf(-(v + mb[o2 - 18])));
    }
    __builtin_amdgcn_s_waitcnt(0);   // drain LDS writes before wave-local reads

    // ---------------- phase 2: deformable sampling + GEMM ------------------
    floatx4 acc0 = {0.f, 0.f, 0.f, 0.f}, acc1 = {0.f, 0.f, 0.f, 0.f};
    floatx4 acc2 = {0.f, 0.f, 0.f, 0.f}, acc3 = {0.f, 0.f, 0.f, 0.f};

#define MKTAP(K, I00, I01, I10, I11, U00, U01, U10, U11) do {                \
    int ky = (K) / 3, kx = (K) - ky * 3;                                     \
    float oy = omw[(2 * (K)) * 16 + pl];                                     \
    float ox = omw[(2 * (K) + 1) * 16 + pl];                                 \
    float mk = omw[(18 + (K)) * 16 + pl];                                    \
    float py = oy + (float)(h + ky - 1);                                     \
    float qx = ox + (float)(xw + kx - 1);                                    \
    float y0f = floorf(py), x0f = floorf(qx);                                \
    float dyy = py - y0f, dxx = qx - x0f;                                    \
    int y0 = (int)y0f, x0 = (int)x0f;                                        \
    int y1 = y0 + 1, x1 = x0 + 1;                                            \
    bool vy0 = (y0 >= 0) & (y0 < HH), vy1 = (y1 >= 0) & (y1 < HH);           \
    bool vx0 = (x0 >= 0) & (x0 < WW), vx1 = (x1 >= 0) & (x1 < WW);           \
    U00 = (vy0 & vx0) ? (1.f - dyy) * (1.f - dxx) * mk : 0.f;                \
    U01 = (vy0 & vx1) ? (1.f - dyy) * dxx * mk : 0.f;                        \
    U10 = (vy1 & vx0) ? dyy * (1.f - dxx) * mk : 0.f;                        \
    U11 = (vy1 & vx1) ? dyy * dxx * mk : 0.f;                                \
    int yc0 = min(max(y0, 0), HH - 1), yc1 = min(max(y1, 0), HH - 1);        \
    int xc0 = min(max(x0, 0), WW - 1), xc1 = min(max(x1, 0), WW - 1);        \
    I00 = ((yc0 * WW + xc0) << 6) + goff;                                    \
    I01 = ((yc0 * WW + xc1) << 6) + goff;                                    \
    I10 = ((yc1 * WW + xc0) << 6) + goff;                                    \
    I11 = ((yc1 * WW + xc1) << 6) + goff;                                    \
} while (0)

#define DECLSET(S)                                                           \
    int i00##S, i01##S, i10##S, i11##S;                                      \
    float u00##S, u01##S, u10##S, u11##S;                                    \
    half8 c00##S, c01##S, c10##S, c11##S, d00##S, d01##S, d10##S, d11##S;

#define PREP(K, S) do {                                                      \
    MKTAP(K, i00##S, i01##S, i10##S, i11##S,                                 \
          u00##S, u01##S, u10##S, u11##S);                                   \
    c00##S = *(const half8*)(xhb + i00##S);                                  \
    c01##S = *(const half8*)(xhb + i01##S);                                  \
    c10##S = *(const half8*)(xhb + i10##S);                                  \
    c11##S = *(const half8*)(xhb + i11##S);                                  \
    d00##S = *(const half8*)(xhb + i00##S + 32);                             \
    d01##S = *(const half8*)(xhb + i01##S + 32);                             \
    d10##S = *(const half8*)(xhb + i10##S + 32);                             \
    d11##S = *(const half8*)(xhb + i11##S + 32);                             \
} while (0)

#define SPLAT8(H) ((half8){(H), (H), (H), (H), (H), (H), (H), (H)})

#define DOTAP(K, S) do {                                                     \
    const _Float16* wk = waf + ((K) << 12) + lane * 8;                       \
    half8 q0 = *(const half8*)(wk + (0 << 9));                               \
    half8 q1 = *(const half8*)(wk + (1 << 9));                               \
    half8 q2 = *(const half8*)(wk + (2 << 9));                               \
    half8 q3 = *(const half8*)(wk + (3 << 9));                               \
    half8 q4 = *(const half8*)(wk + (4 << 9));                               \
    half8 q5 = *(const half8*)(wk + (5 << 9));                               \
    half8 q6 = *(const half8*)(wk + (6 << 9));                               \
    half8 q7 = *(const half8*)(wk + (7 << 9));                               \
    _Float16 h00 = (_Float16)u00##S, h01 = (_Float16)u01##S;                 \
    _Float16 h10 = (_Float16)u10##S, h11 = (_Float16)u11##S;                 \
    half8 U00 = SPLAT8(h00), U01 = SPLAT8(h01);                              \
    half8 U10 = SPLAT8(h10), U11 = SPLAT8(h11);                              \
    half8 bf = c00##S * U00;                                                 \
    bf = bf + c01##S * U01;                                                  \
    bf = bf + c10##S * U10;                                                  \
    bf = bf + c11##S * U11;                                                  \
    acc0 = __builtin_amdgcn_mfma_f32_16x16x32_f16(q0, bf, acc0, 0, 0, 0);    \
    acc1 = __builtin_amdgcn_mfma_f32_16x16x32_f16(q1, bf, acc1, 0, 0, 0);    \
    acc2 = __builtin_amdgcn_mfma_f32_16x16x32_f16(q2, bf, acc2, 0, 0, 0);    \
    acc3 = __builtin_amdgcn_mfma_f32_16x16x32_f16(q3, bf, acc3, 0, 0, 0);    \
    half8 bd = d00##S * U00;                                                 \
    bd = bd + d01##S * U01;                                                  \
    bd = bd + d10##S * U10;                                                  \
    bd = bd + d11##S * U11;                                                  \
    acc0 = __builtin_amdgcn_mfma_f32_16x16x32_f16(q4, bd, acc0, 0, 0, 0);    \
    acc1 = __builtin_amdgcn_mfma_f32_16x16x32_f16(q5, bd, acc1, 0, 0, 0);    \
    acc2 = __builtin_amdgcn_mfma_f32_16x16x32_f16(q6, bd, acc2, 0, 0, 0);    \
    acc3 = __builtin_amdgcn_mfma_f32_16x16x32_f16(q7, bd, acc3, 0, 0, 0);    \
} while (0)

    {
        DECLSET(A)
        DECLSET(B)
        PREP(0, A);
        PREP(1, B);
        DOTAP(0, A); PREP(2, A);
        DOTAP(1, B); PREP(3, B);
        DOTAP(2, A); PREP(4, A);
        DOTAP(3, B); PREP(5, B);
        DOTAP(4, A); PREP(6, A);
        DOTAP(5, B); PREP(7, B);
        DOTAP(6, A); PREP(8, A);
        DOTAP(7, B);
        DOTAP(8, A);
    }

    // epilogue: D col = pl, row o = m*16 + g*4 + j
    float* outp = out + (size_t)b * OO * HWsz + h * WW + p0 + wv * 16 + pl;
#pragma unroll
    for (int j = 0; j < 4; ++j) outp[(size_t)(g * 4 + j) * HWsz] = acc0[j];
#pragma unroll
    for (int j = 0; j < 4; ++j) outp[(size_t)(16 + g * 4 + j) * HWsz] = acc1[j];
#pragma unroll
    for (int j = 0; j < 4; ++j) outp[(size_t)(32 + g * 4 + j) * HWsz] = acc2[j];
#pragma unroll
    for (int j = 0; j < 4; ++j) outp[(size_t)(48 + g * 4 + j) * HWsz] = acc3[j];
}

extern "C" void kernel_launch(void* const* d_in, const int* in_sizes, int n_in,
                              void* d_out, int out_size, void* d_ws, size_t ws_size,
                              hipStream_t stream)
{
    const float* x   = (const float*)d_in[0];
    const float* ow  = (const float*)d_in[1];
    const float* ob  = (const float*)d_in[2];
    const float* mw  = (const float*)d_in[3];
    const float* mb  = (const float*)d_in[4];
    const float* wgt = (const float*)d_in[5];
    float* out = (float*)d_out;

    // ws: xh (4*16384*64 f16 = 8.39MB) | waf (36864 f16) | wcf (18432 f16)
    _Float16* xh  = (_Float16*)d_ws;
    _Float16* waf = xh + (size_t)BB * HWsz * 64;
    _Float16* wcf = waf + 36864;

    pre_kernel<<<dim3(512 + 216), dim3(256), 0, stream>>>(
        x, wgt, ow, mw, xh, waf, wcf);
    fused_kernel<<<dim3(1024), dim3(256), 0, stream>>>(
        xh, waf, wcf, ob, mb, out);
}